// Round 4
// baseline (221.041 us; speedup 1.0000x reference)
//
#include <hip/hip_runtime.h>
#include <hip/hip_bf16.h>
#include <stdint.h>

using bf16 = __hip_bfloat16;
typedef __bf16 bf16x8 __attribute__((ext_vector_type(8)));
typedef float  f32x4  __attribute__((ext_vector_type(4)));
typedef long   i64;
typedef unsigned char u8;

#define AS1 __attribute__((address_space(1)))
#define AS3 __attribute__((address_space(3)))

__device__ __forceinline__ void async_cp16(const void* g, void* l) {
    __builtin_amdgcn_global_load_lds((const AS1 void*)g, (AS3 void*)l, 16, 0, 0);
}

__device__ __forceinline__ unsigned pk8_lo(float a, float b, unsigned old) {
    return __builtin_amdgcn_cvt_pk_fp8_f32(a, b, old, false);
}

// Template-exact sync primitives (m201): builtin s_barrier (no implicit
// vmcnt drain), clobber-free counted waitcnt, sched_barrier(0) pins.
#define SBAR()   do { __builtin_amdgcn_s_barrier(); \
                      __builtin_amdgcn_sched_barrier(0); } while (0)
#define WAITV(N) do { asm volatile("s_waitcnt vmcnt(" #N ")"); \
                      __builtin_amdgcn_sched_barrier(0); } while (0)

// ---------------------------------------------------------------------------
// Fragment loads (granule-XOR swizzle, verified conflict-free:
// SQ_LDS_BANK_CONFLICT == 0). LDS[row][slot] holds global granule slot^(row&7).
// ---------------------------------------------------------------------------
__device__ __forceinline__ void ld_bfrag(const char* lB, int wn, int quad, int r16,
                                         bf16x8 (&bfr)[4][2])
{
#pragma unroll
    for (int nt = 0; nt < 4; nt++) {
        int row = wn + nt * 16 + r16;
#pragma unroll
        for (int kk = 0; kk < 2; kk++) {
            int slot = (kk * 4 + quad) ^ (row & 7);
            bfr[nt][kk] = *(const bf16x8*)(lB + row * 128 + slot * 16);
        }
    }
}

__device__ __forceinline__ void ld_afrag(const char* lA, int wm, int quad, int r16, int q,
                                         bf16x8 (&af)[2][2])
{
#pragma unroll
    for (int t = 0; t < 2; t++) {
        int row = wm + (q * 2 + t) * 16 + r16;
#pragma unroll
        for (int kk = 0; kk < 2; kk++) {
            int slot = (kk * 4 + quad) ^ (row & 7);
            af[t][kk] = *(const bf16x8*)(lA + row * 128 + slot * 16);
        }
    }
}

__device__ __forceinline__ void mfma_quad(int q, bf16x8 (&af)[2][2], bf16x8 (&bfr)[4][2],
                                          f32x4 (&acc)[8][4])
{
    __builtin_amdgcn_s_setprio(1);
#pragma unroll
    for (int mt = 0; mt < 2; mt++)
#pragma unroll
        for (int nt = 0; nt < 4; nt++)
#pragma unroll
            for (int kk = 0; kk < 2; kk++)
                acc[q * 2 + mt][nt] = __builtin_amdgcn_mfma_f32_16x16x32_bf16(
                    af[mt][kk], bfr[nt][kk], acc[q * 2 + mt][nt], 0, 0, 0);
    __builtin_amdgcn_s_setprio(0);
}

// ---------------------------------------------------------------------------
// Fused QKV projection — 256x256 tile, BK=64, 8 waves (2Mx4N, 128x64/wave),
// 8-phase schedule, counted vmcnt, DEEP prefetch via A-depth-3 rotation.
// 160 KiB dynamic LDS: A0@0 A1@32K A2@64K B0@96K B1@128K.
// A buffers addressed as smem + (j%3)*32768 computed at runtime — an
// initialized local array of LDS pointers does not compile on gfx950
// ("unsupported expression in static initializer: addrspacecast").
// grid (12, 32): bn 0-3 -> Q (fp8), 4-7 -> K (fp8), 8-11 -> V (bf16
// transposed into Vt[1024][8192]).
//
// K-tiles j use A[j%3] and B[j%2]. Iter i consumes tiles 2i (ph1-4) and
// 2i+1 (ph5-8). Staging (2 loads/phase/wave, uniform):
//   ph1,2: A(2i+2) -> A[(2i+2)%3]  (region dead since iter i-1 ph8)
//   ph3,4: B(2i+2) -> B0           (dead after ph1's reads)
//   ph5,6: A(2i+3) -> A[2i%3]      (dead after ph4's reads)
//   ph7,8: B(2i+3) -> B1           (dead after ph5's reads)
// FIFO gates: WAITV(8)@ph4 drains A(2i+1)+B(2i+1) (issued iter i-1 ph5-8,
// distance 4-7 phases); WAITV(8)@ph8 drains A(2i+2)+B(2i+2) (issued ph1-4,
// distance 4-7 phases). Every load gets >=4 phases (~2500cy) in flight
// >> 900cy HBM-miss latency. Never drains to 0 mid-loop.
// ---------------------------------------------------------------------------
__global__ __launch_bounds__(512, 2) void gemm_qkv(
    const bf16* __restrict__ xb,
    const bf16* __restrict__ Wqb, const bf16* __restrict__ Wkb, const bf16* __restrict__ Wvb,
    const float* __restrict__ bq, const float* __restrict__ bk, const float* __restrict__ bv,
    u8* __restrict__ Qq, u8* __restrict__ Kq, bf16* __restrict__ Vt)
{
    extern __shared__ char smem[];
    const int bn = blockIdx.x, bm = blockIdx.y;
    const int seg = bn >> 2, bn_loc = bn & 3;
    const bf16*  W    = seg == 0 ? Wqb : (seg == 1 ? Wkb : Wvb);
    const float* bias = seg == 0 ? bq  : (seg == 1 ? bk  : bv);

    const int tid  = threadIdx.x;
    const int wave = tid >> 6, lane = tid & 63;
    const int wm = (wave >> 2) * 128, wn = (wave & 3) * 64;
    const int quad = lane >> 4, r16 = lane & 15;

    char* B0 = smem + 98304;
    char* B1 = smem + 131072;

    const bf16* Ab = xb + (long)bm * 256 * 1024;
    const bf16* Bb = W  + (long)bn_loc * 256 * 1024;

    const int rl  = lane >> 3;             // row within 8-row chunk
    const int cbg = (lane & 7) ^ rl;       // pre-swizzled 16B granule
    const bf16* gA = Ab + (long)(wave * 32 + rl) * 1024 + cbg * 8;
    const bf16* gB = Bb + (long)(wave * 32 + rl) * 1024 + cbg * 8;
    const int woff = wave * 4096;          // wave's 32-row slice in each buffer

    auto stage = [&](char* dst, const bf16* src, int k0, int c) {
        async_cp16(src + (long)c * 8192 + k0, dst + woff + c * 1024);
    };

    f32x4 acc[8][4];
    const f32x4 zero = {0.f, 0.f, 0.f, 0.f};
#pragma unroll
    for (int i = 0; i < 8; i++)
#pragma unroll
        for (int j = 0; j < 4; j++) acc[i][j] = zero;

    // ---- prologue: tiles 0,1; drain tile 0, keep tile 1 in flight ----
#pragma unroll
    for (int c = 0; c < 4; c++) stage(smem, gA, 0, c);              // A[0]
#pragma unroll
    for (int c = 0; c < 4; c++) stage(B0, gB, 0, c);
#pragma unroll
    for (int c = 0; c < 4; c++) stage(smem + 32768, gA, 64, c);     // A[1]
#pragma unroll
    for (int c = 0; c < 4; c++) stage(B1, gB, 64, c);
    WAITV(8);
    SBAR();

    bf16x8 bfr[4][2], af[2][2];
#pragma unroll 1
    for (int i = 0; i < 8; ++i) {
        char* Ae  = smem + ((2 * i) % 3) * 32768;       // tile 2i   (ph1-4)
        char* Ao  = smem + ((2 * i + 1) % 3) * 32768;   // tile 2i+1 (ph5-8)
        char* An0 = smem + ((2 * i + 2) % 3) * 32768;   // stage target ph1-2
        char* An1 = Ae;                 // (2i+3)%3 == (2i)%3, dead after ph4
        const int kE2 = i * 128 + 128;                  // tile 2i+2
        const int kO2 = i * 128 + 192;                  // tile 2i+3
        const bool pre = (i < 7);

        // ---- ph1: B0 all + Ae q0; stage A(2i+2) c0,c1 ----
        ld_bfrag(B0, wn, quad, r16, bfr);
        ld_afrag(Ae, wm, quad, r16, 0, af);
        if (pre) { stage(An0, gA, kE2, 0); stage(An0, gA, kE2, 1); }
        SBAR();
        mfma_quad(0, af, bfr, acc);
        SBAR();
        // ---- ph2: Ae q1; stage A(2i+2) c2,c3 ----
        ld_afrag(Ae, wm, quad, r16, 1, af);
        if (pre) { stage(An0, gA, kE2, 2); stage(An0, gA, kE2, 3); }
        SBAR();
        mfma_quad(1, af, bfr, acc);
        SBAR();
        // ---- ph3: Ae q2; stage B(2i+2) c0,c1 ----
        ld_afrag(Ae, wm, quad, r16, 2, af);
        if (pre) { stage(B0, gB, kE2, 0); stage(B0, gB, kE2, 1); }
        SBAR();
        mfma_quad(2, af, bfr, acc);
        SBAR();
        // ---- ph4: Ae q3; stage B(2i+2) c2,c3; gate odd tile ----
        ld_afrag(Ae, wm, quad, r16, 3, af);
        if (pre) { stage(B0, gB, kE2, 2); stage(B0, gB, kE2, 3); WAITV(8); }
        else     { WAITV(0); }
        SBAR();
        mfma_quad(3, af, bfr, acc);
        SBAR();
        // ---- ph5: B1 all + Ao q0; stage A(2i+3) c0,c1 ----
        ld_bfrag(B1, wn, quad, r16, bfr);
        ld_afrag(Ao, wm, quad, r16, 0, af);
        if (pre) { stage(An1, gA, kO2, 0); stage(An1, gA, kO2, 1); }
        SBAR();
        mfma_quad(0, af, bfr, acc);
        SBAR();
        // ---- ph6: Ao q1; stage A(2i+3) c2,c3 ----
        ld_afrag(Ao, wm, quad, r16, 1, af);
        if (pre) { stage(An1, gA, kO2, 2); stage(An1, gA, kO2, 3); }
        SBAR();
        mfma_quad(1, af, bfr, acc);
        SBAR();
        // ---- ph7: Ao q2; stage B(2i+3) c0,c1 ----
        ld_afrag(Ao, wm, quad, r16, 2, af);
        if (pre) { stage(B1, gB, kO2, 0); stage(B1, gB, kO2, 1); }
        SBAR();
        mfma_quad(2, af, bfr, acc);
        SBAR();
        // ---- ph8: Ao q3; stage B(2i+3) c2,c3; gate next even tile ----
        ld_afrag(Ao, wm, quad, r16, 3, af);
        if (pre) { stage(B1, gB, kO2, 2); stage(B1, gB, kO2, 3); WAITV(8); }
        SBAR();
        mfma_quad(3, af, bfr, acc);
        SBAR();
    }

    // ---- epilogue ----
    if (seg < 2) {
        u8* O = seg == 0 ? Qq : Kq;
#pragma unroll
        for (int mt = 0; mt < 8; mt++) {
#pragma unroll
            for (int nt = 0; nt < 4; nt++) {
                int col = bn_loc * 256 + wn + nt * 16 + r16;
                float badd = bias[col];
#pragma unroll
                for (int rg = 0; rg < 4; rg++) {
                    long token = (long)bm * 256 + wm + mt * 16 + quad * 4 + rg;
                    float v = acc[mt][nt][rg] + badd;
                    O[token * 1024 + col] = (u8)(pk8_lo(v, v, 0u) & 0xFF);
                }
            }
        }
    } else {
#pragma unroll
        for (int mt = 0; mt < 8; mt++) {
#pragma unroll
            for (int nt = 0; nt < 4; nt++) {
                int col = bn_loc * 256 + wn + nt * 16 + r16;
                float badd = bias[col];
                long token0 = (long)bm * 256 + wm + mt * 16 + quad * 4;
                union { ushort4 u; bf16 h[4]; } o;
#pragma unroll
                for (int rg = 0; rg < 4; rg++)
                    o.h[rg] = __float2bfloat16(acc[mt][nt][rg] + badd);
                *(ushort4*)&Vt[(long)col * 8192 + token0] = o.u;   // 8B packed
            }
        }
    }
}

// ---------------------------------------------------------------------------
// Scores + exp, fp8 Q/K, BK=256. P = exp(Q*K^T/32) bf16 (causal-masked 0),
// per-(row,block) sums to spart. Grid (136, 1, 4): linearized lower triangle.
// XCD chunked swizzle (544 = 8*68, bijective): each XCD gets a contiguous
// 68-run of triangle order -> consecutive t share bm -> Q row-block L2-hot.
// ---------------------------------------------------------------------------
__global__ __launch_bounds__(256, 2) void gemm_scores(
    const u8* __restrict__ Qq, const u8* __restrict__ Kq,
    bf16* __restrict__ P, float* __restrict__ spart)
{
    const int lin = blockIdx.x + 136 * blockIdx.z;       // 0..543
    const int ntg = (lin & 7) * 68 + (lin >> 3);         // chunked XCD map
    const int t = ntg % 136, bz = ntg / 136;
    int bm = (int)((sqrtf(8.f * t + 1.f) - 1.f) * 0.5f);
    while ((bm + 1) * (bm + 2) / 2 <= t) bm++;
    while (bm * (bm + 1) / 2 > t) bm--;
    const int bn = t - bm * (bm + 1) / 2;
    const bool diag = (bn == bm);

    __shared__ u8 sA[2][128 * 128];   // 2 x 16 KB
    __shared__ u8 sB[2][128 * 128];

    const int tid  = threadIdx.x;
    const int wave = tid >> 6, lane = tid & 63;
    const int wm = (wave >> 1) * 64, wn = (wave & 1) * 64;
    const int quad = lane >> 4, r16 = lane & 15;
    const int whalf = wave & 1;

    const u8* Ab = Qq + (long)bz * 2048 * 1024 + (long)bm * 128 * 1024;
    const u8* Bb = Kq + (long)bz * 2048 * 1024 + (long)bn * 128 * 1024;

    const int rl = lane >> 3;              // row in 8-row chunk (= row&7)
    const int cb = (lane & 7) ^ rl;        // 16B granule this lane fetches
    const u8* gA = Ab + (long)(wave * 32 + rl) * 1024 + cb * 16;
    const u8* gB = Bb + (long)(wave * 32 + rl) * 1024 + cb * 16;

    f32x4 acc[4][4];
    const f32x4 zero = {0.f, 0.f, 0.f, 0.f};
#pragma unroll
    for (int i = 0; i < 4; i++)
#pragma unroll
        for (int j = 0; j < 4; j++) acc[i][j] = zero;

    for (int it = 0; it < 4; ++it) {
        const int k0 = it * 256;
#pragma unroll
        for (int s = 0; s < 2; s++) {
            u8* lA = sA[s] + wave * 32 * 128;
            u8* lB = sB[s] + wave * 32 * 128;
#pragma unroll
            for (int c = 0; c < 4; c++) {
                async_cp16(gA + (long)c * 8 * 1024 + k0 + s * 128, lA + c * 1024);
                async_cp16(gB + (long)c * 8 * 1024 + k0 + s * 128, lB + c * 1024);
            }
        }
        __syncthreads();
#pragma unroll
        for (int s = 0; s < 2; s++) {
#pragma unroll
            for (int kk = 0; kk < 4; kk++) {
                const int g  = kk * 2 + (quad >> 1);   // 16B granule in k-chunk
                const int hb = (quad & 1) * 8;         // 8B half
                i64 av[4], bv[4];
#pragma unroll
                for (int t2 = 0; t2 < 4; t2++) {
                    int row  = wm + t2 * 16 + r16;
                    int slot = g ^ (row & 7);
                    av[t2] = *(const i64*)(sA[s] + row * 128 + slot * 16 + hb);
                }
#pragma unroll
                for (int t2 = 0; t2 < 4; t2++) {
                    int row  = wn + t2 * 16 + r16;
                    int slot = g ^ (row & 7);
                    bv[t2] = *(const i64*)(sB[s] + row * 128 + slot * 16 + hb);
                }
#pragma unroll
                for (int mt = 0; mt < 4; mt++)
#pragma unroll
                    for (int nt = 0; nt < 4; nt++)
                        acc[mt][nt] = __builtin_amdgcn_mfma_f32_16x16x32_fp8_fp8(
                            av[mt], bv[nt], acc[mt][nt], 0, 0, 0);
            }
        }
        __syncthreads();
    }

    // epilogue: stream exp(s), accumulate per-row sums
    bf16* Pb = P + (long)bz * 2048 * 2048 + (long)bm * 128 * 2048 + bn * 128;
    float rowsum[4][4];
#pragma unroll
    for (int mt = 0; mt < 4; mt++)
#pragma unroll
        for (int rg = 0; rg < 4; rg++) rowsum[mt][rg] = 0.f;

#pragma unroll
    for (int mt = 0; mt < 4; mt++) {
#pragma unroll
        for (int nt = 0; nt < 4; nt++) {
            int rcol = wn + nt * 16 + r16;
#pragma unroll
            for (int rg = 0; rg < 4; rg++) {
                int rrow = wm + mt * 16 + quad * 4 + rg;
                float e = (diag && rcol > rrow)
                            ? 0.f : __expf(acc[mt][nt][rg] * 0.03125f);
                Pb[(long)rrow * 2048 + rcol] = __float2bfloat16(e);
                rowsum[mt][rg] += e;
            }
        }
    }
#pragma unroll
    for (int off = 1; off < 16; off <<= 1)
#pragma unroll
        for (int mt = 0; mt < 4; mt++)
#pragma unroll
            for (int rg = 0; rg < 4; rg++)
                rowsum[mt][rg] += __shfl_xor(rowsum[mt][rg], off);

    float* red = (float*)sA;    // safe: past last core barrier
    if (r16 == 0) {
#pragma unroll
        for (int mt = 0; mt < 4; mt++)
#pragma unroll
            for (int rg = 0; rg < 4; rg++)
                red[whalf * 128 + wm + mt * 16 + quad * 4 + rg] = rowsum[mt][rg];
    }
    __syncthreads();
    if (tid < 128)
        spart[((long)bz * 16 + bn) * 2048 + bm * 128 + tid] = red[tid] + red[128 + tid];
}

// ---------------------------------------------------------------------------
// PV (bf16), BK=128. out[q,:] = (P[q,:] . V) / l[q]. 512 blocks, 2/CU.
// XCD-grouping swizzle: the 8 bn-siblings sharing a P row-block get the same
// lin%8 -> same XCD -> P fetched once per XCD into L2. Pairing preserved:
// lin and lin+256 share by, differ bz by 2 -> bm mapping (bz<2 ? 15-by : by)
// keeps each CU's resident pair at 17 k-tiles total.
// ---------------------------------------------------------------------------
__global__ __launch_bounds__(256, 2) void gemm_pv(
    const bf16* __restrict__ P, const bf16* __restrict__ Vt,
    const float* __restrict__ spart, float* __restrict__ out)
{
    const int lin = blockIdx.x + 8 * blockIdx.y + 128 * blockIdx.z;  // 0..511
    const int xcd = lin & 7;
    const int m   = lin >> 3;
    const int bn  = m & 7;
    const int g   = xcd + 8 * (m >> 3);     // group 0..63 = (by, bz)
    const int by  = g & 15, bz = g >> 4;
    const int bm  = (bz < 2) ? (15 - by) : by;
    const int nb  = bm + 1;

    __shared__ bf16 sA[2][128 * 64];   // 2 x 16 KB
    __shared__ bf16 sB[2][128 * 64];
    __shared__ float invl[128];

    const int tid  = threadIdx.x;
    const int wave = tid >> 6, lane = tid & 63;
    const int wm = (wave >> 1) * 64, wn = (wave & 1) * 64;
    const int quad = lane >> 4, r16 = lane & 15;

    if (tid < 128) {
        long base = (long)bz * 16 * 2048 + (long)bm * 128 + tid;
        float l = 0.f;
        for (int j = 0; j < nb; j++) l += spart[base + j * 2048];
        invl[tid] = 1.f / l;
    }

    const bf16* Ab = P  + (long)bz * 2048 * 2048 + (long)bm * 128 * 2048;
    const bf16* Bb = Vt + (long)bz * 2048 + (long)bn * 128 * 8192;

    const int rl = lane >> 3;
    const int cb = (lane & 7) ^ rl;
    const bf16* gA = Ab + (long)(wave * 32 + rl) * 2048 + cb * 8;
    const bf16* gB = Bb + (long)(wave * 32 + rl) * 8192 + cb * 8;

    f32x4 acc[4][4];
    const f32x4 zero = {0.f, 0.f, 0.f, 0.f};
#pragma unroll
    for (int i = 0; i < 4; i++)
#pragma unroll
        for (int j = 0; j < 4; j++) acc[i][j] = zero;

    for (int it = 0; it < nb; ++it) {
        const int k0 = it * 128;
#pragma unroll
        for (int s = 0; s < 2; s++) {
            char* lA = (char*)sA[s] + wave * 32 * 128;
            char* lB = (char*)sB[s] + wave * 32 * 128;
#pragma unroll
            for (int c = 0; c < 4; c++) {
                async_cp16(gA + (long)c * 8 * 2048 + k0 + s * 64, lA + c * 1024);
                async_cp16(gB + (long)c * 8 * 8192 + k0 + s * 64, lB + c * 1024);
            }
        }
        __syncthreads();
#pragma unroll
        for (int s = 0; s < 2; s++) {
#pragma unroll
            for (int kk = 0; kk < 2; kk++) {
                bf16x8 af[4], bfr[4];
#pragma unroll
                for (int t = 0; t < 4; t++) {
                    int row  = wm + t * 16 + r16;
                    int slot = (kk * 4 + quad) ^ (row & 7);
                    af[t] = *(const bf16x8*)((const char*)sA[s] + row * 128 + slot * 16);
                }
#pragma unroll
                for (int t = 0; t < 4; t++) {
                    int row  = wn + t * 16 + r16;
                    int slot = (kk * 4 + quad) ^ (row & 7);
                    bfr[t] = *(const bf16x8*)((const char*)sB[s] + row * 128 + slot * 16);
                }
#pragma unroll
                for (int mt = 0; mt < 4; mt++)
#pragma unroll
                    for (int nt = 0; nt < 4; nt++)
                        acc[mt][nt] = __builtin_amdgcn_mfma_f32_16x16x32_bf16(
                            af[mt], bfr[nt], acc[mt][nt], 0, 0, 0);
            }
        }
        __syncthreads();
    }

    float* Ob = out + (long)bz * 2048 * 1024 + (long)bm * 128 * 1024 + bn * 128;
#pragma unroll
    for (int mt = 0; mt < 4; mt++) {
#pragma unroll
        for (int nt = 0; nt < 4; nt++) {
            int rcol = wn + nt * 16 + r16;
#pragma unroll
            for (int rg = 0; rg < 4; rg++) {
                int rrow = wm + mt * 16 + quad * 4 + rg;
                Ob[(long)rrow * 1024 + rcol] = acc[mt][nt][rg] * invl[rrow];
            }
        }
    }
}

// Convert x (8192 blocks) and the three weights (3*1024 blocks) to bf16.
__global__ __launch_bounds__(256) void cvt_all(
    const float* __restrict__ x,
    const float* __restrict__ Wq, const float* __restrict__ Wk, const float* __restrict__ Wv,
    bf16* __restrict__ xb, bf16* __restrict__ dq, bf16* __restrict__ dk, bf16* __restrict__ dv)
{
    int b = blockIdx.x;
    const float* s; bf16* d; long off;
    if (b < 8192) { s = x; d = xb; off = (long)b * 1024; }
    else {
        int w = (b - 8192) >> 10, lb = (b - 8192) & 1023;
        s = w == 0 ? Wq : (w == 1 ? Wk : Wv);
        d = w == 0 ? dq : (w == 1 ? dk : dv);
        off = (long)lb * 1024;
    }
    long i = off + threadIdx.x * 4;
    float4 v = *(const float4*)(s + i);
    union { ushort4 u; bf16 h[4]; } o;
    o.h[0] = __float2bfloat16(v.x);
    o.h[1] = __float2bfloat16(v.y);
    o.h[2] = __float2bfloat16(v.z);
    o.h[3] = __float2bfloat16(v.w);
    *(ushort4*)(d + i) = o.u;
}

extern "C" void kernel_launch(void* const* d_in, const int* in_sizes, int n_in,
                              void* d_out, int out_size, void* d_ws, size_t ws_size,
                              hipStream_t stream)
{
    (void)in_sizes; (void)n_in; (void)out_size; (void)ws_size;
    const float* x  = (const float*)d_in[0];
    const float* Wq = (const float*)d_in[1];
    const float* bq = (const float*)d_in[2];
    const float* Wk = (const float*)d_in[3];
    const float* bk = (const float*)d_in[4];
    const float* Wv = (const float*)d_in[5];
    const float* bv = (const float*)d_in[6];
    float* out = (float*)d_out;

    char* ws = (char*)d_ws;
    bf16* xb  = (bf16*)ws;  ws += (long)8192 * 1024 * 2;      // 16 MB
    bf16* Wqb = (bf16*)ws;  ws += (long)1024 * 1024 * 2;
    bf16* Wkb = (bf16*)ws;  ws += (long)1024 * 1024 * 2;
    bf16* Wvb = (bf16*)ws;  ws += (long)1024 * 1024 * 2;
    u8*  Qq   = (u8*)ws;    ws += (long)8192 * 1024;          //  8 MB
    u8*  Kq   = (u8*)ws;    ws += (long)8192 * 1024;
    bf16* Vt  = (bf16*)ws;  ws += (long)8192 * 1024 * 2;      // 16 MB, V^T [1024][8192]
    bf16* P   = (bf16*)ws;  ws += (long)4 * 2048 * 2048 * 2;  // 32 MB
    float* spart = (float*)ws; ws += (long)4 * 16 * 2048 * 4;

    static bool attr_set = false;
    if (!attr_set) {
        (void)hipFuncSetAttribute(reinterpret_cast<const void*>(gemm_qkv),
                                  hipFuncAttributeMaxDynamicSharedMemorySize, 163840);
        attr_set = true;
    }

    cvt_all<<<8192 + 3072, 256, 0, stream>>>(x, Wq, Wk, Wv, xb, Wqb, Wkb, Wvb);

    gemm_qkv<<<dim3(12, 32), 512, 163840, stream>>>(
        xb, Wqb, Wkb, Wvb, bq, bk, bv, Qq, Kq, Vt);

    gemm_scores<<<dim3(136, 1, 4), 256, 0, stream>>>(Qq, Kq, P, spart);

    gemm_pv<<<dim3(8, 16, 4), 256, 0, stream>>>(P, Vt, spart, out);
}

// Round 6
// 214.632 us; speedup vs baseline: 1.0299x; 1.0299x over previous
//
#include <hip/hip_runtime.h>
#include <hip/hip_bf16.h>
#include <stdint.h>

using bf16 = __hip_bfloat16;
typedef __bf16 bf16x8 __attribute__((ext_vector_type(8)));
typedef float  f32x4  __attribute__((ext_vector_type(4)));
typedef int    i32x4  __attribute__((ext_vector_type(4)));
typedef long   i64;
typedef unsigned char u8;
typedef unsigned long long u64;

#define AS1 __attribute__((address_space(1)))
#define AS3 __attribute__((address_space(3)))

__device__ __forceinline__ void async_cp16(const void* g, void* l) {
    __builtin_amdgcn_global_load_lds((const AS1 void*)g, (AS3 void*)l, 16, 0, 0);
}

__device__ __forceinline__ unsigned pk8_lo(float a, float b, unsigned old) {
    return __builtin_amdgcn_cvt_pk_fp8_f32(a, b, old, false);
}

// ---------------------------------------------------------------------------
// Fused QKV projection — verified round-0 m97-structure core (128x128 tile,
// BK=64, 4 waves, 2 blocks/CU). Epilogues route through a 32 KB LDS bounce so
// global stores are contiguous per 16-lane group (was 1 B/lane for Q/K,
// 8 B stride-16K for Vt). grid (24, 64): bn 0-7 -> Q (fp8), 8-15 -> K (fp8),
// 16-23 -> V (bf16, transposed into Vt[1024][8192]).
// ROUND-5 BUGFIX: Vt bounce granule index was missing the wave token-offset
// term (wm>>3); waves 2-3 overwrote waves 0-1's granules -> absmax 2.96.
// ---------------------------------------------------------------------------
__global__ __launch_bounds__(256, 2) void gemm_qkv(
    const bf16* __restrict__ xb,
    const bf16* __restrict__ Wqb, const bf16* __restrict__ Wkb, const bf16* __restrict__ Wvb,
    const float* __restrict__ bq, const float* __restrict__ bk, const float* __restrict__ bv,
    u8* __restrict__ Qq, u8* __restrict__ Kq, bf16* __restrict__ Vt)
{
    __shared__ char qsm[32768];            // sA @0 (16K), sB @16K; epilogue bounce
    const int bn = blockIdx.x, bm = blockIdx.y;
    const int seg = bn >> 3, bn_loc = bn & 7;
    const bf16*  W    = seg == 0 ? Wqb : (seg == 1 ? Wkb : Wvb);
    const float* bias = seg == 0 ? bq  : (seg == 1 ? bk  : bv);

    const int tid  = threadIdx.x;
    const int wave = tid >> 6, lane = tid & 63;
    const int wm = (wave >> 1) * 64, wn = (wave & 1) * 64;
    const int quad = lane >> 4, r16 = lane & 15;
    const int lane16 = r16;

    const bf16* Ab = xb + (long)bm * 128 * 1024;
    const bf16* Bb = W  + (long)bn_loc * 128 * 1024;

    const int rl = lane >> 3;
    const int cb = (lane & 7) ^ rl;
    const bf16* gA = Ab + (long)(wave * 32 + rl) * 1024 + cb * 8;
    const bf16* gB = Bb + (long)(wave * 32 + rl) * 1024 + cb * 8;
    char* lA = qsm         + wave * 32 * 128;
    char* lB = qsm + 16384 + wave * 32 * 128;

    f32x4 acc[4][4];
    const f32x4 zero = {0.f, 0.f, 0.f, 0.f};
#pragma unroll
    for (int i = 0; i < 4; i++)
#pragma unroll
        for (int j = 0; j < 4; j++) acc[i][j] = zero;

    for (int k0 = 0; k0 < 1024; k0 += 64) {
#pragma unroll
        for (int c = 0; c < 4; c++) {
            async_cp16(gA + (long)c * 8 * 1024 + k0, lA + c * 1024);
            async_cp16(gB + (long)c * 8 * 1024 + k0, lB + c * 1024);
        }
        __syncthreads();
#pragma unroll
        for (int kk = 0; kk < 2; kk++) {
            bf16x8 af[4], bfr[4];
#pragma unroll
            for (int t = 0; t < 4; t++) {
                int row  = wm + t * 16 + r16;
                int slot = (kk * 4 + quad) ^ (row & 7);
                af[t] = *(const bf16x8*)(qsm + row * 128 + slot * 16);
            }
#pragma unroll
            for (int t = 0; t < 4; t++) {
                int row  = wn + t * 16 + r16;
                int slot = (kk * 4 + quad) ^ (row & 7);
                bfr[t] = *(const bf16x8*)(qsm + 16384 + row * 128 + slot * 16);
            }
#pragma unroll
            for (int mt = 0; mt < 4; mt++)
#pragma unroll
                for (int nt = 0; nt < 4; nt++)
                    acc[mt][nt] = __builtin_amdgcn_mfma_f32_16x16x32_bf16(
                        af[mt], bfr[nt], acc[mt][nt], 0, 0, 0);
        }
        __syncthreads();
    }
    // last loop iteration ended with __syncthreads -> qsm free for bounce

    if (seg < 2) {
        // ---- Q/K fp8 bounce: LDS [128][136B]. Then 16-lane rows -> 8B/lane
        // contiguous 128B global segments (was 1 B/lane). ----
        u8* O = seg == 0 ? Qq : Kq;
#pragma unroll
        for (int mt = 0; mt < 4; mt++) {
#pragma unroll
            for (int nt = 0; nt < 4; nt++) {
                int lcol = wn + nt * 16 + r16;
                float badd = bias[bn_loc * 128 + lcol];
#pragma unroll
                for (int rg = 0; rg < 4; rg++) {
                    int lrow = wm + mt * 16 + quad * 4 + rg;
                    float v = acc[mt][nt][rg] + badd;
                    qsm[lrow * 136 + lcol] = (u8)(pk8_lo(v, v, 0u) & 0xFF);
                }
            }
        }
        __syncthreads();
#pragma unroll
        for (int j = 0; j < 8; j++) {
            int lrow = (tid >> 4) + j * 16;
            u64 v = *(const u64*)(qsm + lrow * 136 + lane16 * 8);
            *(u64*)&O[((long)bm * 128 + lrow) * 1024 + bn_loc * 128 + lane16 * 8] = v;
        }
    } else {
        // ---- Vt bounce: LDS [128 col][256B tokens], 16B-granule XOR swizzle
        // (g ^ (col&7), low-3-bit involution; granule = wm/8 + mt*2 + quad/2).
        // Then 16-lane rows -> 16B/lane contiguous 256B global segments. ----
#pragma unroll
        for (int mt = 0; mt < 4; mt++) {
#pragma unroll
            for (int nt = 0; nt < 4; nt++) {
                int lcol = wn + nt * 16 + r16;
                float badd = bias[bn_loc * 128 + lcol];
                union { ushort4 u; bf16 h[4]; } o;
#pragma unroll
                for (int rg = 0; rg < 4; rg++)
                    o.h[rg] = __float2bfloat16(acc[mt][nt][rg] + badd);
                int g16 = ((wm >> 3) + mt * 2 + (quad >> 1)) ^ (lcol & 7);  // FIX: +wm>>3
                *(ushort4*)(qsm + lcol * 256 + g16 * 16 + (quad & 1) * 8) = o.u;
            }
        }
        __syncthreads();
#pragma unroll
        for (int j = 0; j < 8; j++) {
            int lcol = (tid >> 4) + j * 16;
            int g = lane16 ^ (lcol & 7);
            i32x4 v = *(const i32x4*)(qsm + lcol * 256 + g * 16);
            *(i32x4*)&Vt[((long)bn_loc * 128 + lcol) * 8192 + (long)bm * 128 + lane16 * 8] = v;
        }
    }
}

// ---------------------------------------------------------------------------
// Scores + exp, fp8 Q/K, BK=256. P = exp(Q*K^T/32) bf16 (causal-masked 0),
// per-(row,block) sums to spart. Grid (136, 1, 4): linearized lower triangle.
// XCD chunked swizzle (544 = 8*68, bijective). P written via LDS bounce
// (272B rows) -> 16-lane full-row stores, 16B/lane, 256B segments.
// ---------------------------------------------------------------------------
__global__ __launch_bounds__(256, 2) void gemm_scores(
    const u8* __restrict__ Qq, const u8* __restrict__ Kq,
    bf16* __restrict__ P, float* __restrict__ spart)
{
    __shared__ char ssm[65536];            // sA @0 (2x16K), sB @32K (2x16K)
    const int lin = blockIdx.x + 136 * blockIdx.z;       // 0..543
    const int ntg = (lin & 7) * 68 + (lin >> 3);         // chunked XCD map
    const int t = ntg % 136, bz = ntg / 136;
    int bm = (int)((sqrtf(8.f * t + 1.f) - 1.f) * 0.5f);
    while ((bm + 1) * (bm + 2) / 2 <= t) bm++;
    while (bm * (bm + 1) / 2 > t) bm--;
    const int bn = t - bm * (bm + 1) / 2;
    const bool diag = (bn == bm);

    const int tid  = threadIdx.x;
    const int wave = tid >> 6, lane = tid & 63;
    const int wm = (wave >> 1) * 64, wn = (wave & 1) * 64;
    const int quad = lane >> 4, r16 = lane & 15;
    const int lane16 = r16;
    const int whalf = wave & 1;

    const u8* Ab = Qq + (long)bz * 2048 * 1024 + (long)bm * 128 * 1024;
    const u8* Bb = Kq + (long)bz * 2048 * 1024 + (long)bn * 128 * 1024;

    const int rl = lane >> 3;              // row in 8-row chunk (= row&7)
    const int cb = (lane & 7) ^ rl;        // 16B granule this lane fetches
    const u8* gA = Ab + (long)(wave * 32 + rl) * 1024 + cb * 16;
    const u8* gB = Bb + (long)(wave * 32 + rl) * 1024 + cb * 16;

    f32x4 acc[4][4];
    const f32x4 zero = {0.f, 0.f, 0.f, 0.f};
#pragma unroll
    for (int i = 0; i < 4; i++)
#pragma unroll
        for (int j = 0; j < 4; j++) acc[i][j] = zero;

    for (int it = 0; it < 4; ++it) {
        const int k0 = it * 256;
#pragma unroll
        for (int s = 0; s < 2; s++) {
            char* lA = ssm + s * 16384         + wave * 32 * 128;
            char* lB = ssm + 32768 + s * 16384 + wave * 32 * 128;
#pragma unroll
            for (int c = 0; c < 4; c++) {
                async_cp16(gA + (long)c * 8 * 1024 + k0 + s * 128, lA + c * 1024);
                async_cp16(gB + (long)c * 8 * 1024 + k0 + s * 128, lB + c * 1024);
            }
        }
        __syncthreads();
#pragma unroll
        for (int s = 0; s < 2; s++) {
#pragma unroll
            for (int kk = 0; kk < 4; kk++) {
                const int g  = kk * 2 + (quad >> 1);   // 16B granule in k-chunk
                const int hb = (quad & 1) * 8;         // 8B half
                i64 av[4], bv[4];
#pragma unroll
                for (int t2 = 0; t2 < 4; t2++) {
                    int row  = wm + t2 * 16 + r16;
                    int slot = g ^ (row & 7);
                    av[t2] = *(const i64*)(ssm + s * 16384 + row * 128 + slot * 16 + hb);
                }
#pragma unroll
                for (int t2 = 0; t2 < 4; t2++) {
                    int row  = wn + t2 * 16 + r16;
                    int slot = g ^ (row & 7);
                    bv[t2] = *(const i64*)(ssm + 32768 + s * 16384 + row * 128 + slot * 16 + hb);
                }
#pragma unroll
                for (int mt = 0; mt < 4; mt++)
#pragma unroll
                    for (int nt = 0; nt < 4; nt++)
                        acc[mt][nt] = __builtin_amdgcn_mfma_f32_16x16x32_fp8_fp8(
                            av[mt], bv[nt], acc[mt][nt], 0, 0, 0);
            }
        }
        __syncthreads();
    }
    // main loop done (ends with barrier) -> ssm free for bounce.
    // P tile buffer: [128 rows][272B]; red floats at +34816.

    float rowsum[4][4];
#pragma unroll
    for (int mt = 0; mt < 4; mt++)
#pragma unroll
        for (int rg = 0; rg < 4; rg++) rowsum[mt][rg] = 0.f;

#pragma unroll
    for (int mt = 0; mt < 4; mt++) {
#pragma unroll
        for (int nt = 0; nt < 4; nt++) {
            int rcol = wn + nt * 16 + r16;
#pragma unroll
            for (int rg = 0; rg < 4; rg++) {
                int rrow = wm + mt * 16 + quad * 4 + rg;
                float e = (diag && rcol > rrow)
                            ? 0.f : __expf(acc[mt][nt][rg] * 0.03125f);
                *(bf16*)(ssm + rrow * 272 + rcol * 2) = __float2bfloat16(e);
                rowsum[mt][rg] += e;
            }
        }
    }
#pragma unroll
    for (int off = 1; off < 16; off <<= 1)
#pragma unroll
        for (int mt = 0; mt < 4; mt++)
#pragma unroll
            for (int rg = 0; rg < 4; rg++)
                rowsum[mt][rg] += __shfl_xor(rowsum[mt][rg], off);

    float* red = (float*)(ssm + 34816);
    if (r16 == 0) {
#pragma unroll
        for (int mt = 0; mt < 4; mt++)
#pragma unroll
            for (int rg = 0; rg < 4; rg++)
                red[whalf * 128 + wm + mt * 16 + quad * 4 + rg] = rowsum[mt][rg];
    }
    __syncthreads();
    if (tid < 128)
        spart[((long)bz * 16 + bn) * 2048 + bm * 128 + tid] = red[tid] + red[128 + tid];

    bf16* Pb = P + (long)bz * 2048 * 2048 + (long)bm * 128 * 2048 + bn * 128;
#pragma unroll
    for (int j = 0; j < 8; j++) {
        int prow = (tid >> 4) + j * 16;
        i32x4 v = *(const i32x4*)(ssm + prow * 272 + lane16 * 16);
        *(i32x4*)&Pb[(long)prow * 2048 + lane16 * 8] = v;
    }
}

// ---------------------------------------------------------------------------
// PV (bf16), BK=128. out[q,:] = (P[q,:] . V) / l[q]. 512 blocks, 2/CU.
// XCD-grouping swizzle: the 8 bn-siblings sharing a P row-block get the same
// lin%8 -> same XCD -> P fetched once per XCD into L2. Pairing preserved:
// lin and lin+256 share by, differ bz by 2 -> bm mapping (bz<2 ? 15-by : by)
// keeps each CU's resident pair at 17 k-tiles total.
// ---------------------------------------------------------------------------
__global__ __launch_bounds__(256, 2) void gemm_pv(
    const bf16* __restrict__ P, const bf16* __restrict__ Vt,
    const float* __restrict__ spart, float* __restrict__ out)
{
    const int lin = blockIdx.x + 8 * blockIdx.y + 128 * blockIdx.z;  // 0..511
    const int xcd = lin & 7;
    const int m   = lin >> 3;
    const int bn  = m & 7;
    const int g   = xcd + 8 * (m >> 3);     // group 0..63 = (by, bz)
    const int by  = g & 15, bz = g >> 4;
    const int bm  = (bz < 2) ? (15 - by) : by;
    const int nb  = bm + 1;

    __shared__ bf16 sA[2][128 * 64];   // 2 x 16 KB
    __shared__ bf16 sB[2][128 * 64];
    __shared__ float invl[128];

    const int tid  = threadIdx.x;
    const int wave = tid >> 6, lane = tid & 63;
    const int wm = (wave >> 1) * 64, wn = (wave & 1) * 64;
    const int quad = lane >> 4, r16 = lane & 15;

    if (tid < 128) {
        long base = (long)bz * 16 * 2048 + (long)bm * 128 + tid;
        float l = 0.f;
        for (int j = 0; j < nb; j++) l += spart[base + j * 2048];
        invl[tid] = 1.f / l;
    }

    const bf16* Ab = P  + (long)bz * 2048 * 2048 + (long)bm * 128 * 2048;
    const bf16* Bb = Vt + (long)bz * 2048 + (long)bn * 128 * 8192;

    const int rl = lane >> 3;
    const int cb = (lane & 7) ^ rl;
    const bf16* gA = Ab + (long)(wave * 32 + rl) * 2048 + cb * 8;
    const bf16* gB = Bb + (long)(wave * 32 + rl) * 8192 + cb * 8;

    f32x4 acc[4][4];
    const f32x4 zero = {0.f, 0.f, 0.f, 0.f};
#pragma unroll
    for (int i = 0; i < 4; i++)
#pragma unroll
        for (int j = 0; j < 4; j++) acc[i][j] = zero;

    for (int it = 0; it < nb; ++it) {
        const int k0 = it * 128;
#pragma unroll
        for (int s = 0; s < 2; s++) {
            char* lA = (char*)sA[s] + wave * 32 * 128;
            char* lB = (char*)sB[s] + wave * 32 * 128;
#pragma unroll
            for (int c = 0; c < 4; c++) {
                async_cp16(gA + (long)c * 8 * 2048 + k0 + s * 64, lA + c * 1024);
                async_cp16(gB + (long)c * 8 * 8192 + k0 + s * 64, lB + c * 1024);
            }
        }
        __syncthreads();
#pragma unroll
        for (int s = 0; s < 2; s++) {
#pragma unroll
            for (int kk = 0; kk < 2; kk++) {
                bf16x8 af[4], bfr[4];
#pragma unroll
                for (int t = 0; t < 4; t++) {
                    int row  = wm + t * 16 + r16;
                    int slot = (kk * 4 + quad) ^ (row & 7);
                    af[t] = *(const bf16x8*)((const char*)sA[s] + row * 128 + slot * 16);
                }
#pragma unroll
                for (int t = 0; t < 4; t++) {
                    int row  = wn + t * 16 + r16;
                    int slot = (kk * 4 + quad) ^ (row & 7);
                    bfr[t] = *(const bf16x8*)((const char*)sB[s] + row * 128 + slot * 16);
                }
#pragma unroll
                for (int mt = 0; mt < 4; mt++)
#pragma unroll
                    for (int nt = 0; nt < 4; nt++)
                        acc[mt][nt] = __builtin_amdgcn_mfma_f32_16x16x32_bf16(
                            af[mt], bfr[nt], acc[mt][nt], 0, 0, 0);
            }
        }
        __syncthreads();
    }

    float* Ob = out + (long)bz * 2048 * 1024 + (long)bm * 128 * 1024 + bn * 128;
#pragma unroll
    for (int mt = 0; mt < 4; mt++) {
#pragma unroll
        for (int nt = 0; nt < 4; nt++) {
            int rcol = wn + nt * 16 + r16;
#pragma unroll
            for (int rg = 0; rg < 4; rg++) {
                int rrow = wm + mt * 16 + quad * 4 + rg;
                Ob[(long)rrow * 1024 + rcol] = acc[mt][nt][rg] * invl[rrow];
            }
        }
    }
}

// Convert x (8192 blocks) and the three weights (3*1024 blocks) to bf16.
__global__ __launch_bounds__(256) void cvt_all(
    const float* __restrict__ x,
    const float* __restrict__ Wq, const float* __restrict__ Wk, const float* __restrict__ Wv,
    bf16* __restrict__ xb, bf16* __restrict__ dq, bf16* __restrict__ dk, bf16* __restrict__ dv)
{
    int b = blockIdx.x;
    const float* s; bf16* d; long off;
    if (b < 8192) { s = x; d = xb; off = (long)b * 1024; }
    else {
        int w = (b - 8192) >> 10, lb = (b - 8192) & 1023;
        s = w == 0 ? Wq : (w == 1 ? Wk : Wv);
        d = w == 0 ? dq : (w == 1 ? dk : dv);
        off = (long)lb * 1024;
    }
    long i = off + threadIdx.x * 4;
    float4 v = *(const float4*)(s + i);
    union { ushort4 u; bf16 h[4]; } o;
    o.h[0] = __float2bfloat16(v.x);
    o.h[1] = __float2bfloat16(v.y);
    o.h[2] = __float2bfloat16(v.z);
    o.h[3] = __float2bfloat16(v.w);
    *(ushort4*)(d + i) = o.u;
}

extern "C" void kernel_launch(void* const* d_in, const int* in_sizes, int n_in,
                              void* d_out, int out_size, void* d_ws, size_t ws_size,
                              hipStream_t stream)
{
    (void)in_sizes; (void)n_in; (void)out_size; (void)ws_size;
    const float* x  = (const float*)d_in[0];
    const float* Wq = (const float*)d_in[1];
    const float* bq = (const float*)d_in[2];
    const float* Wk = (const float*)d_in[3];
    const float* bk = (const float*)d_in[4];
    const float* Wv = (const float*)d_in[5];
    const float* bv = (const float*)d_in[6];
    float* out = (float*)d_out;

    char* ws = (char*)d_ws;
    bf16* xb  = (bf16*)ws;  ws += (long)8192 * 1024 * 2;      // 16 MB
    bf16* Wqb = (bf16*)ws;  ws += (long)1024 * 1024 * 2;
    bf16* Wkb = (bf16*)ws;  ws += (long)1024 * 1024 * 2;
    bf16* Wvb = (bf16*)ws;  ws += (long)1024 * 1024 * 2;
    u8*  Qq   = (u8*)ws;    ws += (long)8192 * 1024;          //  8 MB
    u8*  Kq   = (u8*)ws;    ws += (long)8192 * 1024;
    bf16* Vt  = (bf16*)ws;  ws += (long)8192 * 1024 * 2;      // 16 MB, V^T [1024][8192]
    bf16* P   = (bf16*)ws;  ws += (long)4 * 2048 * 2048 * 2;  // 32 MB
    float* spart = (float*)ws; ws += (long)4 * 16 * 2048 * 4;

    cvt_all<<<8192 + 3072, 256, 0, stream>>>(x, Wq, Wk, Wv, xb, Wqb, Wkb, Wvb);

    gemm_qkv<<<dim3(24, 64), 256, 0, stream>>>(
        xb, Wqb, Wkb, Wvb, bq, bk, bv, Qq, Kq, Vt);

    gemm_scores<<<dim3(136, 1, 4), 256, 0, stream>>>(Qq, Kq, P, spart);

    gemm_pv<<<dim3(8, 16, 4), 256, 0, stream>>>(P, Vt, spart, out);
}

// Round 8
// 210.912 us; speedup vs baseline: 1.0480x; 1.0176x over previous
//
#include <hip/hip_runtime.h>
#include <hip/hip_bf16.h>
#include <stdint.h>

using bf16 = __hip_bfloat16;
typedef __bf16 bf16x8 __attribute__((ext_vector_type(8)));
typedef float  f32x4  __attribute__((ext_vector_type(4)));
typedef int    i32x4  __attribute__((ext_vector_type(4)));
typedef long   i64;
typedef unsigned char u8;
typedef unsigned long long u64;

#define AS1 __attribute__((address_space(1)))
#define AS3 __attribute__((address_space(3)))

__device__ __forceinline__ void async_cp16(const void* g, void* l) {
    __builtin_amdgcn_global_load_lds((const AS1 void*)g, (AS3 void*)l, 16, 0, 0);
}

__device__ __forceinline__ unsigned pk8_lo(float a, float b, unsigned old) {
    return __builtin_amdgcn_cvt_pk_fp8_f32(a, b, old, false);
}

// ---------------------------------------------------------------------------
// Fused QKV projection — verified m97-structure core (128x128 tile, BK=64,
// 4 waves, 2 blocks/CU) + LDS-bounce epilogues (round-6 verified, 55.1 us).
// V output bf16 (fp8 V failed error budget in round 7: early causal rows have
// n_eff~1, no error averaging -> e4m3's 6% rel err lands directly on out).
// grid (24, 64): bn 0-7 -> Q (fp8), 8-15 -> K (fp8), 16-23 -> V (bf16 transp).
// ---------------------------------------------------------------------------
__global__ __launch_bounds__(256, 2) void gemm_qkv(
    const bf16* __restrict__ xb,
    const bf16* __restrict__ Wqb, const bf16* __restrict__ Wkb, const bf16* __restrict__ Wvb,
    const float* __restrict__ bq, const float* __restrict__ bk, const float* __restrict__ bv,
    u8* __restrict__ Qq, u8* __restrict__ Kq, bf16* __restrict__ Vt)
{
    __shared__ char qsm[32768];            // sA @0 (16K), sB @16K; epilogue bounce
    const int bn = blockIdx.x, bm = blockIdx.y;
    const int seg = bn >> 3, bn_loc = bn & 7;
    const bf16*  W    = seg == 0 ? Wqb : (seg == 1 ? Wkb : Wvb);
    const float* bias = seg == 0 ? bq  : (seg == 1 ? bk  : bv);

    const int tid  = threadIdx.x;
    const int wave = tid >> 6, lane = tid & 63;
    const int wm = (wave >> 1) * 64, wn = (wave & 1) * 64;
    const int quad = lane >> 4, r16 = lane & 15;
    const int lane16 = r16;

    const bf16* Ab = xb + (long)bm * 128 * 1024;
    const bf16* Bb = W  + (long)bn_loc * 128 * 1024;

    const int rl = lane >> 3;
    const int cb = (lane & 7) ^ rl;
    const bf16* gA = Ab + (long)(wave * 32 + rl) * 1024 + cb * 8;
    const bf16* gB = Bb + (long)(wave * 32 + rl) * 1024 + cb * 8;
    char* lA = qsm         + wave * 32 * 128;
    char* lB = qsm + 16384 + wave * 32 * 128;

    f32x4 acc[4][4];
    const f32x4 zero = {0.f, 0.f, 0.f, 0.f};
#pragma unroll
    for (int i = 0; i < 4; i++)
#pragma unroll
        for (int j = 0; j < 4; j++) acc[i][j] = zero;

    for (int k0 = 0; k0 < 1024; k0 += 64) {
#pragma unroll
        for (int c = 0; c < 4; c++) {
            async_cp16(gA + (long)c * 8 * 1024 + k0, lA + c * 1024);
            async_cp16(gB + (long)c * 8 * 1024 + k0, lB + c * 1024);
        }
        __syncthreads();
#pragma unroll
        for (int kk = 0; kk < 2; kk++) {
            bf16x8 af[4], bfr[4];
#pragma unroll
            for (int t = 0; t < 4; t++) {
                int row  = wm + t * 16 + r16;
                int slot = (kk * 4 + quad) ^ (row & 7);
                af[t] = *(const bf16x8*)(qsm + row * 128 + slot * 16);
            }
#pragma unroll
            for (int t = 0; t < 4; t++) {
                int row  = wn + t * 16 + r16;
                int slot = (kk * 4 + quad) ^ (row & 7);
                bfr[t] = *(const bf16x8*)(qsm + 16384 + row * 128 + slot * 16);
            }
#pragma unroll
            for (int mt = 0; mt < 4; mt++)
#pragma unroll
                for (int nt = 0; nt < 4; nt++)
                    acc[mt][nt] = __builtin_amdgcn_mfma_f32_16x16x32_bf16(
                        af[mt], bfr[nt], acc[mt][nt], 0, 0, 0);
        }
        __syncthreads();
    }
    // last loop iteration ended with __syncthreads -> qsm free for bounce

    if (seg < 2) {
        // ---- Q/K fp8 bounce: LDS [128][136B]; 16-lane rows -> 8B/lane
        // contiguous 128B global segments. ----
        u8* O = seg == 0 ? Qq : Kq;
#pragma unroll
        for (int mt = 0; mt < 4; mt++) {
#pragma unroll
            for (int nt = 0; nt < 4; nt++) {
                int lcol = wn + nt * 16 + r16;
                float badd = bias[bn_loc * 128 + lcol];
#pragma unroll
                for (int rg = 0; rg < 4; rg++) {
                    int lrow = wm + mt * 16 + quad * 4 + rg;
                    float v = acc[mt][nt][rg] + badd;
                    qsm[lrow * 136 + lcol] = (u8)(pk8_lo(v, v, 0u) & 0xFF);
                }
            }
        }
        __syncthreads();
#pragma unroll
        for (int j = 0; j < 8; j++) {
            int lrow = (tid >> 4) + j * 16;
            u64 v = *(const u64*)(qsm + lrow * 136 + lane16 * 8);
            *(u64*)&O[((long)bm * 128 + lrow) * 1024 + bn_loc * 128 + lane16 * 8] = v;
        }
    } else {
        // ---- Vt bounce: LDS [128 col][256B tokens], 16B-granule XOR swizzle
        // (g ^ (col&7); granule = wm/8 + mt*2 + quad/2, verified round 6). ----
#pragma unroll
        for (int mt = 0; mt < 4; mt++) {
#pragma unroll
            for (int nt = 0; nt < 4; nt++) {
                int lcol = wn + nt * 16 + r16;
                float badd = bias[bn_loc * 128 + lcol];
                union { ushort4 u; bf16 h[4]; } o;
#pragma unroll
                for (int rg = 0; rg < 4; rg++)
                    o.h[rg] = __float2bfloat16(acc[mt][nt][rg] + badd);
                int g16 = ((wm >> 3) + mt * 2 + (quad >> 1)) ^ (lcol & 7);
                *(ushort4*)(qsm + lcol * 256 + g16 * 16 + (quad & 1) * 8) = o.u;
            }
        }
        __syncthreads();
#pragma unroll
        for (int j = 0; j < 8; j++) {
            int lcol = (tid >> 4) + j * 16;
            int g = lane16 ^ (lcol & 7);
            i32x4 v = *(const i32x4*)(qsm + lcol * 256 + g * 16);
            *(i32x4*)&Vt[((long)bn_loc * 128 + lcol) * 8192 + (long)bm * 128 + lane16 * 8] = v;
        }
    }
}

// ---------------------------------------------------------------------------
// Scores + exp, fp8 Q/K, BK=256. P = exp(Q*K^T/32) bf16 (causal-masked 0),
// per-(row,block) sums to spart. Grid (136, 1, 4): linearized lower triangle.
// XCD chunked swizzle (544 = 8*68, bijective). P written via LDS bounce
// (272B rows) -> 16-lane full-row stores, 16B/lane, 256B segments.
// ---------------------------------------------------------------------------
__global__ __launch_bounds__(256, 2) void gemm_scores(
    const u8* __restrict__ Qq, const u8* __restrict__ Kq,
    bf16* __restrict__ P, float* __restrict__ spart)
{
    __shared__ char ssm[65536];            // sA @0 (2x16K), sB @32K (2x16K)
    const int lin = blockIdx.x + 136 * blockIdx.z;       // 0..543
    const int ntg = (lin & 7) * 68 + (lin >> 3);         // chunked XCD map
    const int t = ntg % 136, bz = ntg / 136;
    int bm = (int)((sqrtf(8.f * t + 1.f) - 1.f) * 0.5f);
    while ((bm + 1) * (bm + 2) / 2 <= t) bm++;
    while (bm * (bm + 1) / 2 > t) bm--;
    const int bn = t - bm * (bm + 1) / 2;
    const bool diag = (bn == bm);

    const int tid  = threadIdx.x;
    const int wave = tid >> 6, lane = tid & 63;
    const int wm = (wave >> 1) * 64, wn = (wave & 1) * 64;
    const int quad = lane >> 4, r16 = lane & 15;
    const int lane16 = r16;
    const int whalf = wave & 1;

    const u8* Ab = Qq + (long)bz * 2048 * 1024 + (long)bm * 128 * 1024;
    const u8* Bb = Kq + (long)bz * 2048 * 1024 + (long)bn * 128 * 1024;

    const int rl = lane >> 3;              // row in 8-row chunk (= row&7)
    const int cb = (lane & 7) ^ rl;        // 16B granule this lane fetches
    const u8* gA = Ab + (long)(wave * 32 + rl) * 1024 + cb * 16;
    const u8* gB = Bb + (long)(wave * 32 + rl) * 1024 + cb * 16;

    f32x4 acc[4][4];
    const f32x4 zero = {0.f, 0.f, 0.f, 0.f};
#pragma unroll
    for (int i = 0; i < 4; i++)
#pragma unroll
        for (int j = 0; j < 4; j++) acc[i][j] = zero;

    for (int it = 0; it < 4; ++it) {
        const int k0 = it * 256;
#pragma unroll
        for (int s = 0; s < 2; s++) {
            char* lA = ssm + s * 16384         + wave * 32 * 128;
            char* lB = ssm + 32768 + s * 16384 + wave * 32 * 128;
#pragma unroll
            for (int c = 0; c < 4; c++) {
                async_cp16(gA + (long)c * 8 * 1024 + k0 + s * 128, lA + c * 1024);
                async_cp16(gB + (long)c * 8 * 1024 + k0 + s * 128, lB + c * 1024);
            }
        }
        __syncthreads();
#pragma unroll
        for (int s = 0; s < 2; s++) {
#pragma unroll
            for (int kk = 0; kk < 4; kk++) {
                const int g  = kk * 2 + (quad >> 1);   // 16B granule in k-chunk
                const int hb = (quad & 1) * 8;         // 8B half
                i64 av[4], bv[4];
#pragma unroll
                for (int t2 = 0; t2 < 4; t2++) {
                    int row  = wm + t2 * 16 + r16;
                    int slot = g ^ (row & 7);
                    av[t2] = *(const i64*)(ssm + s * 16384 + row * 128 + slot * 16 + hb);
                }
#pragma unroll
                for (int t2 = 0; t2 < 4; t2++) {
                    int row  = wn + t2 * 16 + r16;
                    int slot = g ^ (row & 7);
                    bv[t2] = *(const i64*)(ssm + 32768 + s * 16384 + row * 128 + slot * 16 + hb);
                }
#pragma unroll
                for (int mt = 0; mt < 4; mt++)
#pragma unroll
                    for (int nt = 0; nt < 4; nt++)
                        acc[mt][nt] = __builtin_amdgcn_mfma_f32_16x16x32_fp8_fp8(
                            av[mt], bv[nt], acc[mt][nt], 0, 0, 0);
            }
        }
        __syncthreads();
    }
    // main loop done (ends with barrier) -> ssm free for bounce.
    // P tile buffer: [128 rows][272B]; red floats at +34816.

    float rowsum[4][4];
#pragma unroll
    for (int mt = 0; mt < 4; mt++)
#pragma unroll
        for (int rg = 0; rg < 4; rg++) rowsum[mt][rg] = 0.f;

#pragma unroll
    for (int mt = 0; mt < 4; mt++) {
#pragma unroll
        for (int nt = 0; nt < 4; nt++) {
            int rcol = wn + nt * 16 + r16;
#pragma unroll
            for (int rg = 0; rg < 4; rg++) {
                int rrow = wm + mt * 16 + quad * 4 + rg;
                float e = (diag && rcol > rrow)
                            ? 0.f : __expf(acc[mt][nt][rg] * 0.03125f);
                *(bf16*)(ssm + rrow * 272 + rcol * 2) = __float2bfloat16(e);
                rowsum[mt][rg] += e;
            }
        }
    }
#pragma unroll
    for (int off = 1; off < 16; off <<= 1)
#pragma unroll
        for (int mt = 0; mt < 4; mt++)
#pragma unroll
            for (int rg = 0; rg < 4; rg++)
                rowsum[mt][rg] += __shfl_xor(rowsum[mt][rg], off);

    float* red = (float*)(ssm + 34816);
    if (r16 == 0) {
#pragma unroll
        for (int mt = 0; mt < 4; mt++)
#pragma unroll
            for (int rg = 0; rg < 4; rg++)
                red[whalf * 128 + wm + mt * 16 + quad * 4 + rg] = rowsum[mt][rg];
    }
    __syncthreads();
    if (tid < 128)
        spart[((long)bz * 16 + bn) * 2048 + bm * 128 + tid] = red[tid] + red[128 + tid];

    bf16* Pb = P + (long)bz * 2048 * 2048 + (long)bm * 128 * 2048 + bn * 128;
#pragma unroll
    for (int j = 0; j < 8; j++) {
        int prow = (tid >> 4) + j * 16;
        i32x4 v = *(const i32x4*)(ssm + prow * 272 + lane16 * 16);
        *(i32x4*)&Pb[(long)prow * 2048 + lane16 * 8] = v;
    }
}

// ---------------------------------------------------------------------------
// PV (bf16), BK=128. out[q,:] = (P[q,:] . V) / l[q]. 512 blocks, 2/CU.
// SWIZZLE CHANGE (this round): natural order groups by bn per XCD
// (lin%8 = bn = XCD): each XCD keeps ONE 2 MB Vt slice L2-resident across
// its 64 blocks (fits 4 MB L2) while P rows stream. The previous P-grouping
// forced 8 distinct Vt slices (16 MB) through each 4 MB L2 -> thrash.
// Complementary-bm pairing preserved: lin and lin+256 share bn,by and differ
// bz by 2 -> bm = (bz<2 ? 15-by : by) gives every CU pair 17 k-tiles.
// ---------------------------------------------------------------------------
__global__ __launch_bounds__(256, 2) void gemm_pv(
    const bf16* __restrict__ P, const bf16* __restrict__ Vt,
    const float* __restrict__ spart, float* __restrict__ out)
{
    const int bn = blockIdx.x, by = blockIdx.y, bz = blockIdx.z;
    const int bm = (bz < 2) ? (15 - by) : by;
    const int nb = bm + 1;

    __shared__ bf16 sA[2][128 * 64];   // 2 x 16 KB
    __shared__ bf16 sB[2][128 * 64];
    __shared__ float invl[128];

    const int tid  = threadIdx.x;
    const int wave = tid >> 6, lane = tid & 63;
    const int wm = (wave >> 1) * 64, wn = (wave & 1) * 64;
    const int quad = lane >> 4, r16 = lane & 15;

    if (tid < 128) {
        long base = (long)bz * 16 * 2048 + (long)bm * 128 + tid;
        float l = 0.f;
        for (int j = 0; j < nb; j++) l += spart[base + j * 2048];
        invl[tid] = 1.f / l;
    }

    const bf16* Ab = P  + (long)bz * 2048 * 2048 + (long)bm * 128 * 2048;
    const bf16* Bb = Vt + (long)bz * 2048 + (long)bn * 128 * 8192;

    const int rl = lane >> 3;
    const int cb = (lane & 7) ^ rl;
    const bf16* gA = Ab + (long)(wave * 32 + rl) * 2048 + cb * 8;
    const bf16* gB = Bb + (long)(wave * 32 + rl) * 8192 + cb * 8;

    f32x4 acc[4][4];
    const f32x4 zero = {0.f, 0.f, 0.f, 0.f};
#pragma unroll
    for (int i = 0; i < 4; i++)
#pragma unroll
        for (int j = 0; j < 4; j++) acc[i][j] = zero;

    for (int it = 0; it < nb; ++it) {
        const int k0 = it * 128;
#pragma unroll
        for (int s = 0; s < 2; s++) {
            char* lA = (char*)sA[s] + wave * 32 * 128;
            char* lB = (char*)sB[s] + wave * 32 * 128;
#pragma unroll
            for (int c = 0; c < 4; c++) {
                async_cp16(gA + (long)c * 8 * 2048 + k0 + s * 64, lA + c * 1024);
                async_cp16(gB + (long)c * 8 * 8192 + k0 + s * 64, lB + c * 1024);
            }
        }
        __syncthreads();
#pragma unroll
        for (int s = 0; s < 2; s++) {
#pragma unroll
            for (int kk = 0; kk < 2; kk++) {
                bf16x8 af[4], bfr[4];
#pragma unroll
                for (int t = 0; t < 4; t++) {
                    int row  = wm + t * 16 + r16;
                    int slot = (kk * 4 + quad) ^ (row & 7);
                    af[t] = *(const bf16x8*)((const char*)sA[s] + row * 128 + slot * 16);
                }
#pragma unroll
                for (int t = 0; t < 4; t++) {
                    int row  = wn + t * 16 + r16;
                    int slot = (kk * 4 + quad) ^ (row & 7);
                    bfr[t] = *(const bf16x8*)((const char*)sB[s] + row * 128 + slot * 16);
                }
#pragma unroll
                for (int mt = 0; mt < 4; mt++)
#pragma unroll
                    for (int nt = 0; nt < 4; nt++)
                        acc[mt][nt] = __builtin_amdgcn_mfma_f32_16x16x32_bf16(
                            af[mt], bfr[nt], acc[mt][nt], 0, 0, 0);
            }
        }
        __syncthreads();
    }

    float* Ob = out + (long)bz * 2048 * 1024 + (long)bm * 128 * 1024 + bn * 128;
#pragma unroll
    for (int mt = 0; mt < 4; mt++) {
#pragma unroll
        for (int nt = 0; nt < 4; nt++) {
            int rcol = wn + nt * 16 + r16;
#pragma unroll
            for (int rg = 0; rg < 4; rg++) {
                int rrow = wm + mt * 16 + quad * 4 + rg;
                Ob[(long)rrow * 1024 + rcol] = acc[mt][nt][rg] * invl[rrow];
            }
        }
    }
}

// Convert x (8192 blocks) and the three weights (3*1024 blocks) to bf16.
__global__ __launch_bounds__(256) void cvt_all(
    const float* __restrict__ x,
    const float* __restrict__ Wq, const float* __restrict__ Wk, const float* __restrict__ Wv,
    bf16* __restrict__ xb, bf16* __restrict__ dq, bf16* __restrict__ dk, bf16* __restrict__ dv)
{
    int b = blockIdx.x;
    const float* s; bf16* d; long off;
    if (b < 8192) { s = x; d = xb; off = (long)b * 1024; }
    else {
        int w = (b - 8192) >> 10, lb = (b - 8192) & 1023;
        s = w == 0 ? Wq : (w == 1 ? Wk : Wv);
        d = w == 0 ? dq : (w == 1 ? dk : dv);
        off = (long)lb * 1024;
    }
    long i = off + threadIdx.x * 4;
    float4 v = *(const float4*)(s + i);
    union { ushort4 u; bf16 h[4]; } o;
    o.h[0] = __float2bfloat16(v.x);
    o.h[1] = __float2bfloat16(v.y);
    o.h[2] = __float2bfloat16(v.z);
    o.h[3] = __float2bfloat16(v.w);
    *(ushort4*)(d + i) = o.u;
}

extern "C" void kernel_launch(void* const* d_in, const int* in_sizes, int n_in,
                              void* d_out, int out_size, void* d_ws, size_t ws_size,
                              hipStream_t stream)
{
    (void)in_sizes; (void)n_in; (void)out_size; (void)ws_size;
    const float* x  = (const float*)d_in[0];
    const float* Wq = (const float*)d_in[1];
    const float* bq = (const float*)d_in[2];
    const float* Wk = (const float*)d_in[3];
    const float* bk = (const float*)d_in[4];
    const float* Wv = (const float*)d_in[5];
    const float* bv = (const float*)d_in[6];
    float* out = (float*)d_out;

    char* ws = (char*)d_ws;
    bf16* xb  = (bf16*)ws;  ws += (long)8192 * 1024 * 2;      // 16 MB
    bf16* Wqb = (bf16*)ws;  ws += (long)1024 * 1024 * 2;
    bf16* Wkb = (bf16*)ws;  ws += (long)1024 * 1024 * 2;
    bf16* Wvb = (bf16*)ws;  ws += (long)1024 * 1024 * 2;
    u8*  Qq   = (u8*)ws;    ws += (long)8192 * 1024;          //  8 MB
    u8*  Kq   = (u8*)ws;    ws += (long)8192 * 1024;
    bf16* Vt  = (bf16*)ws;  ws += (long)8192 * 1024 * 2;      // 16 MB, V^T [1024][8192]
    bf16* P   = (bf16*)ws;  ws += (long)4 * 2048 * 2048 * 2;  // 32 MB
    float* spart = (float*)ws; ws += (long)4 * 16 * 2048 * 4;

    cvt_all<<<8192 + 3072, 256, 0, stream>>>(x, Wq, Wk, Wv, xb, Wqb, Wkb, Wvb);

    gemm_qkv<<<dim3(24, 64), 256, 0, stream>>>(
        xb, Wqb, Wkb, Wvb, bq, bk, bv, Qq, Kq, Vt);

    gemm_scores<<<dim3(136, 1, 4), 256, 0, stream>>>(Qq, Kq, P, spart);

    gemm_pv<<<dim3(8, 16, 4), 256, 0, stream>>>(P, Vt, spart, out);
}

// Round 9
// 209.853 us; speedup vs baseline: 1.0533x; 1.0050x over previous
//
#include <hip/hip_runtime.h>
#include <hip/hip_bf16.h>
#include <stdint.h>

using bf16 = __hip_bfloat16;
typedef __bf16 bf16x8 __attribute__((ext_vector_type(8)));
typedef float  f32x4  __attribute__((ext_vector_type(4)));
typedef int    i32x4  __attribute__((ext_vector_type(4)));
typedef long   i64;
typedef unsigned char u8;
typedef unsigned long long u64;

#define AS1 __attribute__((address_space(1)))
#define AS3 __attribute__((address_space(3)))

__device__ __forceinline__ void async_cp16(const void* g, void* l) {
    __builtin_amdgcn_global_load_lds((const AS1 void*)g, (AS3 void*)l, 16, 0, 0);
}

__device__ __forceinline__ unsigned pk8_lo(float a, float b, unsigned old) {
    return __builtin_amdgcn_cvt_pk_fp8_f32(a, b, old, false);
}

// ---------------------------------------------------------------------------
// Fused QKV projection — m97-structure core, NOW with BK=128 via two staged
// BK=64 sub-buffers per barrier-pair (the exact coarsening scores/pv already
// use and verify: stage both halves -> one __syncthreads -> consume both).
// Barrier-pairs 16 -> 8. LDS 64 KB (sA0@0 sA1@16K sB0@32K sB1@48K), still
// 2 blocks/CU (128 KB <= 160 KB). Fragment path per sub-buffer is
// byte-identical to the verified round-6 kernel. LDS-bounce epilogues kept.
// grid (24, 64): bn 0-7 -> Q (fp8), 8-15 -> K (fp8), 16-23 -> V (bf16 transp).
// ---------------------------------------------------------------------------
__global__ __launch_bounds__(256, 2) void gemm_qkv(
    const bf16* __restrict__ xb,
    const bf16* __restrict__ Wqb, const bf16* __restrict__ Wkb, const bf16* __restrict__ Wvb,
    const float* __restrict__ bq, const float* __restrict__ bk, const float* __restrict__ bv,
    u8* __restrict__ Qq, u8* __restrict__ Kq, bf16* __restrict__ Vt)
{
    __shared__ char qsm[65536];   // sA0 @0, sA1 @16K, sB0 @32K, sB1 @48K
    const int bn = blockIdx.x, bm = blockIdx.y;
    const int seg = bn >> 3, bn_loc = bn & 7;
    const bf16*  W    = seg == 0 ? Wqb : (seg == 1 ? Wkb : Wvb);
    const float* bias = seg == 0 ? bq  : (seg == 1 ? bk  : bv);

    const int tid  = threadIdx.x;
    const int wave = tid >> 6, lane = tid & 63;
    const int wm = (wave >> 1) * 64, wn = (wave & 1) * 64;
    const int quad = lane >> 4, r16 = lane & 15;
    const int lane16 = r16;

    const bf16* Ab = xb + (long)bm * 128 * 1024;
    const bf16* Bb = W  + (long)bn_loc * 128 * 1024;

    const int rl = lane >> 3;
    const int cb = (lane & 7) ^ rl;
    const bf16* gA = Ab + (long)(wave * 32 + rl) * 1024 + cb * 8;
    const bf16* gB = Bb + (long)(wave * 32 + rl) * 1024 + cb * 8;

    f32x4 acc[4][4];
    const f32x4 zero = {0.f, 0.f, 0.f, 0.f};
#pragma unroll
    for (int i = 0; i < 4; i++)
#pragma unroll
        for (int j = 0; j < 4; j++) acc[i][j] = zero;

    for (int k0 = 0; k0 < 1024; k0 += 128) {
#pragma unroll
        for (int s = 0; s < 2; s++) {
            char* lA = qsm + s * 16384         + wave * 32 * 128;
            char* lB = qsm + 32768 + s * 16384 + wave * 32 * 128;
#pragma unroll
            for (int c = 0; c < 4; c++) {
                async_cp16(gA + (long)c * 8 * 1024 + k0 + s * 64, lA + c * 1024);
                async_cp16(gB + (long)c * 8 * 1024 + k0 + s * 64, lB + c * 1024);
            }
        }
        __syncthreads();
#pragma unroll
        for (int s = 0; s < 2; s++) {
#pragma unroll
            for (int kk = 0; kk < 2; kk++) {
                bf16x8 af[4], bfr[4];
#pragma unroll
                for (int t = 0; t < 4; t++) {
                    int row  = wm + t * 16 + r16;
                    int slot = (kk * 4 + quad) ^ (row & 7);
                    af[t] = *(const bf16x8*)(qsm + s * 16384 + row * 128 + slot * 16);
                }
#pragma unroll
                for (int t = 0; t < 4; t++) {
                    int row  = wn + t * 16 + r16;
                    int slot = (kk * 4 + quad) ^ (row & 7);
                    bfr[t] = *(const bf16x8*)(qsm + 32768 + s * 16384 + row * 128 + slot * 16);
                }
#pragma unroll
                for (int mt = 0; mt < 4; mt++)
#pragma unroll
                    for (int nt = 0; nt < 4; nt++)
                        acc[mt][nt] = __builtin_amdgcn_mfma_f32_16x16x32_bf16(
                            af[mt], bfr[nt], acc[mt][nt], 0, 0, 0);
            }
        }
        __syncthreads();
    }
    // loop ends with __syncthreads -> qsm free for epilogue bounce

    if (seg < 2) {
        // ---- Q/K fp8 bounce: LDS [128][136B]; 16-lane rows -> 8B/lane
        // contiguous 128B global segments. (verified round 6) ----
        u8* O = seg == 0 ? Qq : Kq;
#pragma unroll
        for (int mt = 0; mt < 4; mt++) {
#pragma unroll
            for (int nt = 0; nt < 4; nt++) {
                int lcol = wn + nt * 16 + r16;
                float badd = bias[bn_loc * 128 + lcol];
#pragma unroll
                for (int rg = 0; rg < 4; rg++) {
                    int lrow = wm + mt * 16 + quad * 4 + rg;
                    float v = acc[mt][nt][rg] + badd;
                    qsm[lrow * 136 + lcol] = (u8)(pk8_lo(v, v, 0u) & 0xFF);
                }
            }
        }
        __syncthreads();
#pragma unroll
        for (int j = 0; j < 8; j++) {
            int lrow = (tid >> 4) + j * 16;
            u64 v = *(const u64*)(qsm + lrow * 136 + lane16 * 8);
            *(u64*)&O[((long)bm * 128 + lrow) * 1024 + bn_loc * 128 + lane16 * 8] = v;
        }
    } else {
        // ---- Vt bounce: LDS [128 col][256B tokens], 16B-granule XOR swizzle
        // (g ^ (col&7); granule = wm/8 + mt*2 + quad/2, verified round 6). ----
#pragma unroll
        for (int mt = 0; mt < 4; mt++) {
#pragma unroll
            for (int nt = 0; nt < 4; nt++) {
                int lcol = wn + nt * 16 + r16;
                float badd = bias[bn_loc * 128 + lcol];
                union { ushort4 u; bf16 h[4]; } o;
#pragma unroll
                for (int rg = 0; rg < 4; rg++)
                    o.h[rg] = __float2bfloat16(acc[mt][nt][rg] + badd);
                int g16 = ((wm >> 3) + mt * 2 + (quad >> 1)) ^ (lcol & 7);
                *(ushort4*)(qsm + lcol * 256 + g16 * 16 + (quad & 1) * 8) = o.u;
            }
        }
        __syncthreads();
#pragma unroll
        for (int j = 0; j < 8; j++) {
            int lcol = (tid >> 4) + j * 16;
            int g = lane16 ^ (lcol & 7);
            i32x4 v = *(const i32x4*)(qsm + lcol * 256 + g * 16);
            *(i32x4*)&Vt[((long)bn_loc * 128 + lcol) * 8192 + (long)bm * 128 + lane16 * 8] = v;
        }
    }
}

// ---------------------------------------------------------------------------
// Scores + exp, fp8 Q/K, BK=256. P = exp(Q*K^T/32) bf16 (causal-masked 0),
// per-(row,block) sums to spart. Grid (136, 1, 4): linearized lower triangle.
// XCD chunked swizzle (544 = 8*68, bijective). P written via LDS bounce
// (272B rows) -> 16-lane full-row stores, 16B/lane, 256B segments.
// ---------------------------------------------------------------------------
__global__ __launch_bounds__(256, 2) void gemm_scores(
    const u8* __restrict__ Qq, const u8* __restrict__ Kq,
    bf16* __restrict__ P, float* __restrict__ spart)
{
    __shared__ char ssm[65536];            // sA @0 (2x16K), sB @32K (2x16K)
    const int lin = blockIdx.x + 136 * blockIdx.z;       // 0..543
    const int ntg = (lin & 7) * 68 + (lin >> 3);         // chunked XCD map
    const int t = ntg % 136, bz = ntg / 136;
    int bm = (int)((sqrtf(8.f * t + 1.f) - 1.f) * 0.5f);
    while ((bm + 1) * (bm + 2) / 2 <= t) bm++;
    while (bm * (bm + 1) / 2 > t) bm--;
    const int bn = t - bm * (bm + 1) / 2;
    const bool diag = (bn == bm);

    const int tid  = threadIdx.x;
    const int wave = tid >> 6, lane = tid & 63;
    const int wm = (wave >> 1) * 64, wn = (wave & 1) * 64;
    const int quad = lane >> 4, r16 = lane & 15;
    const int lane16 = r16;
    const int whalf = wave & 1;

    const u8* Ab = Qq + (long)bz * 2048 * 1024 + (long)bm * 128 * 1024;
    const u8* Bb = Kq + (long)bz * 2048 * 1024 + (long)bn * 128 * 1024;

    const int rl = lane >> 3;              // row in 8-row chunk (= row&7)
    const int cb = (lane & 7) ^ rl;        // 16B granule this lane fetches
    const u8* gA = Ab + (long)(wave * 32 + rl) * 1024 + cb * 16;
    const u8* gB = Bb + (long)(wave * 32 + rl) * 1024 + cb * 16;

    f32x4 acc[4][4];
    const f32x4 zero = {0.f, 0.f, 0.f, 0.f};
#pragma unroll
    for (int i = 0; i < 4; i++)
#pragma unroll
        for (int j = 0; j < 4; j++) acc[i][j] = zero;

    for (int it = 0; it < 4; ++it) {
        const int k0 = it * 256;
#pragma unroll
        for (int s = 0; s < 2; s++) {
            char* lA = ssm + s * 16384         + wave * 32 * 128;
            char* lB = ssm + 32768 + s * 16384 + wave * 32 * 128;
#pragma unroll
            for (int c = 0; c < 4; c++) {
                async_cp16(gA + (long)c * 8 * 1024 + k0 + s * 128, lA + c * 1024);
                async_cp16(gB + (long)c * 8 * 1024 + k0 + s * 128, lB + c * 1024);
            }
        }
        __syncthreads();
#pragma unroll
        for (int s = 0; s < 2; s++) {
#pragma unroll
            for (int kk = 0; kk < 4; kk++) {
                const int g  = kk * 2 + (quad >> 1);   // 16B granule in k-chunk
                const int hb = (quad & 1) * 8;         // 8B half
                i64 av[4], bv[4];
#pragma unroll
                for (int t2 = 0; t2 < 4; t2++) {
                    int row  = wm + t2 * 16 + r16;
                    int slot = g ^ (row & 7);
                    av[t2] = *(const i64*)(ssm + s * 16384 + row * 128 + slot * 16 + hb);
                }
#pragma unroll
                for (int t2 = 0; t2 < 4; t2++) {
                    int row  = wn + t2 * 16 + r16;
                    int slot = g ^ (row & 7);
                    bv[t2] = *(const i64*)(ssm + 32768 + s * 16384 + row * 128 + slot * 16 + hb);
                }
#pragma unroll
                for (int mt = 0; mt < 4; mt++)
#pragma unroll
                    for (int nt = 0; nt < 4; nt++)
                        acc[mt][nt] = __builtin_amdgcn_mfma_f32_16x16x32_fp8_fp8(
                            av[mt], bv[nt], acc[mt][nt], 0, 0, 0);
            }
        }
        __syncthreads();
    }
    // main loop done (ends with barrier) -> ssm free for bounce.
    // P tile buffer: [128 rows][272B]; red floats at +34816.

    float rowsum[4][4];
#pragma unroll
    for (int mt = 0; mt < 4; mt++)
#pragma unroll
        for (int rg = 0; rg < 4; rg++) rowsum[mt][rg] = 0.f;

#pragma unroll
    for (int mt = 0; mt < 4; mt++) {
#pragma unroll
        for (int nt = 0; nt < 4; nt++) {
            int rcol = wn + nt * 16 + r16;
#pragma unroll
            for (int rg = 0; rg < 4; rg++) {
                int rrow = wm + mt * 16 + quad * 4 + rg;
                float e = (diag && rcol > rrow)
                            ? 0.f : __expf(acc[mt][nt][rg] * 0.03125f);
                *(bf16*)(ssm + rrow * 272 + rcol * 2) = __float2bfloat16(e);
                rowsum[mt][rg] += e;
            }
        }
    }
#pragma unroll
    for (int off = 1; off < 16; off <<= 1)
#pragma unroll
        for (int mt = 0; mt < 4; mt++)
#pragma unroll
            for (int rg = 0; rg < 4; rg++)
                rowsum[mt][rg] += __shfl_xor(rowsum[mt][rg], off);

    float* red = (float*)(ssm + 34816);
    if (r16 == 0) {
#pragma unroll
        for (int mt = 0; mt < 4; mt++)
#pragma unroll
            for (int rg = 0; rg < 4; rg++)
                red[whalf * 128 + wm + mt * 16 + quad * 4 + rg] = rowsum[mt][rg];
    }
    __syncthreads();
    if (tid < 128)
        spart[((long)bz * 16 + bn) * 2048 + bm * 128 + tid] = red[tid] + red[128 + tid];

    bf16* Pb = P + (long)bz * 2048 * 2048 + (long)bm * 128 * 2048 + bn * 128;
#pragma unroll
    for (int j = 0; j < 8; j++) {
        int prow = (tid >> 4) + j * 16;
        i32x4 v = *(const i32x4*)(ssm + prow * 272 + lane16 * 16);
        *(i32x4*)&Pb[(long)prow * 2048 + lane16 * 8] = v;
    }
}

// ---------------------------------------------------------------------------
// PV (bf16), BK=128. out[q,:] = (P[q,:] . V) / l[q]. 512 blocks, 2/CU.
// Natural order groups by bn per XCD (lin%8 = bn = XCD): each XCD keeps ONE
// 2 MB Vt slice L2-resident while P rows stream (round-8 verified win).
// Complementary-bm pairing: lin and lin+256 share bn,by, differ bz by 2 ->
// bm = (bz<2 ? 15-by : by) gives every CU pair 17 k-tiles.
// ---------------------------------------------------------------------------
__global__ __launch_bounds__(256, 2) void gemm_pv(
    const bf16* __restrict__ P, const bf16* __restrict__ Vt,
    const float* __restrict__ spart, float* __restrict__ out)
{
    const int bn = blockIdx.x, by = blockIdx.y, bz = blockIdx.z;
    const int bm = (bz < 2) ? (15 - by) : by;
    const int nb = bm + 1;

    __shared__ bf16 sA[2][128 * 64];   // 2 x 16 KB
    __shared__ bf16 sB[2][128 * 64];
    __shared__ float invl[128];

    const int tid  = threadIdx.x;
    const int wave = tid >> 6, lane = tid & 63;
    const int wm = (wave >> 1) * 64, wn = (wave & 1) * 64;
    const int quad = lane >> 4, r16 = lane & 15;

    if (tid < 128) {
        long base = (long)bz * 16 * 2048 + (long)bm * 128 + tid;
        float l = 0.f;
        for (int j = 0; j < nb; j++) l += spart[base + j * 2048];
        invl[tid] = 1.f / l;
    }

    const bf16* Ab = P  + (long)bz * 2048 * 2048 + (long)bm * 128 * 2048;
    const bf16* Bb = Vt + (long)bz * 2048 + (long)bn * 128 * 8192;

    const int rl = lane >> 3;
    const int cb = (lane & 7) ^ rl;
    const bf16* gA = Ab + (long)(wave * 32 + rl) * 2048 + cb * 8;
    const bf16* gB = Bb + (long)(wave * 32 + rl) * 8192 + cb * 8;

    f32x4 acc[4][4];
    const f32x4 zero = {0.f, 0.f, 0.f, 0.f};
#pragma unroll
    for (int i = 0; i < 4; i++)
#pragma unroll
        for (int j = 0; j < 4; j++) acc[i][j] = zero;

    for (int it = 0; it < nb; ++it) {
        const int k0 = it * 128;
#pragma unroll
        for (int s = 0; s < 2; s++) {
            char* lA = (char*)sA[s] + wave * 32 * 128;
            char* lB = (char*)sB[s] + wave * 32 * 128;
#pragma unroll
            for (int c = 0; c < 4; c++) {
                async_cp16(gA + (long)c * 8 * 2048 + k0 + s * 64, lA + c * 1024);
                async_cp16(gB + (long)c * 8 * 8192 + k0 + s * 64, lB + c * 1024);
            }
        }
        __syncthreads();
#pragma unroll
        for (int s = 0; s < 2; s++) {
#pragma unroll
            for (int kk = 0; kk < 2; kk++) {
                bf16x8 af[4], bfr[4];
#pragma unroll
                for (int t = 0; t < 4; t++) {
                    int row  = wm + t * 16 + r16;
                    int slot = (kk * 4 + quad) ^ (row & 7);
                    af[t] = *(const bf16x8*)((const char*)sA[s] + row * 128 + slot * 16);
                }
#pragma unroll
                for (int t = 0; t < 4; t++) {
                    int row  = wn + t * 16 + r16;
                    int slot = (kk * 4 + quad) ^ (row & 7);
                    bfr[t] = *(const bf16x8*)((const char*)sB[s] + row * 128 + slot * 16);
                }
#pragma unroll
                for (int mt = 0; mt < 4; mt++)
#pragma unroll
                    for (int nt = 0; nt < 4; nt++)
                        acc[mt][nt] = __builtin_amdgcn_mfma_f32_16x16x32_bf16(
                            af[mt], bfr[nt], acc[mt][nt], 0, 0, 0);
            }
        }
        __syncthreads();
    }

    float* Ob = out + (long)bz * 2048 * 1024 + (long)bm * 128 * 1024 + bn * 128;
#pragma unroll
    for (int mt = 0; mt < 4; mt++) {
#pragma unroll
        for (int nt = 0; nt < 4; nt++) {
            int rcol = wn + nt * 16 + r16;
#pragma unroll
            for (int rg = 0; rg < 4; rg++) {
                int rrow = wm + mt * 16 + quad * 4 + rg;
                Ob[(long)rrow * 1024 + rcol] = acc[mt][nt][rg] * invl[rrow];
            }
        }
    }
}

// Convert x (8192 blocks) and the three weights (3*1024 blocks) to bf16.
__global__ __launch_bounds__(256) void cvt_all(
    const float* __restrict__ x,
    const float* __restrict__ Wq, const float* __restrict__ Wk, const float* __restrict__ Wv,
    bf16* __restrict__ xb, bf16* __restrict__ dq, bf16* __restrict__ dk, bf16* __restrict__ dv)
{
    int b = blockIdx.x;
    const float* s; bf16* d; long off;
    if (b < 8192) { s = x; d = xb; off = (long)b * 1024; }
    else {
        int w = (b - 8192) >> 10, lb = (b - 8192) & 1023;
        s = w == 0 ? Wq : (w == 1 ? Wk : Wv);
        d = w == 0 ? dq : (w == 1 ? dk : dv);
        off = (long)lb * 1024;
    }
    long i = off + threadIdx.x * 4;
    float4 v = *(const float4*)(s + i);
    union { ushort4 u; bf16 h[4]; } o;
    o.h[0] = __float2bfloat16(v.x);
    o.h[1] = __float2bfloat16(v.y);
    o.h[2] = __float2bfloat16(v.z);
    o.h[3] = __float2bfloat16(v.w);
    *(ushort4*)(d + i) = o.u;
}

extern "C" void kernel_launch(void* const* d_in, const int* in_sizes, int n_in,
                              void* d_out, int out_size, void* d_ws, size_t ws_size,
                              hipStream_t stream)
{
    (void)in_sizes; (void)n_in; (void)out_size; (void)ws_size;
    const float* x  = (const float*)d_in[0];
    const float* Wq = (const float*)d_in[1];
    const float* bq = (const float*)d_in[2];
    const float* Wk = (const float*)d_in[3];
    const float* bk = (const float*)d_in[4];
    const float* Wv = (const float*)d_in[5];
    const float* bv = (const float*)d_in[6];
    float* out = (float*)d_out;

    char* ws = (char*)d_ws;
    bf16* xb  = (bf16*)ws;  ws += (long)8192 * 1024 * 2;      // 16 MB
    bf16* Wqb = (bf16*)ws;  ws += (long)1024 * 1024 * 2;
    bf16* Wkb = (bf16*)ws;  ws += (long)1024 * 1024 * 2;
    bf16* Wvb = (bf16*)ws;  ws += (long)1024 * 1024 * 2;
    u8*  Qq   = (u8*)ws;    ws += (long)8192 * 1024;          //  8 MB
    u8*  Kq   = (u8*)ws;    ws += (long)8192 * 1024;
    bf16* Vt  = (bf16*)ws;  ws += (long)8192 * 1024 * 2;      // 16 MB, V^T [1024][8192]
    bf16* P   = (bf16*)ws;  ws += (long)4 * 2048 * 2048 * 2;  // 32 MB
    float* spart = (float*)ws; ws += (long)4 * 16 * 2048 * 4;

    cvt_all<<<8192 + 3072, 256, 0, stream>>>(x, Wq, Wk, Wv, xb, Wqb, Wkb, Wvb);

    gemm_qkv<<<dim3(24, 64), 256, 0, stream>>>(
        xb, Wqb, Wkb, Wvb, bq, bk, bv, Qq, Kq, Vt);

    gemm_scores<<<dim3(136, 1, 4), 256, 0, stream>>>(Qq, Kq, P, spart);

    gemm_pv<<<dim3(8, 16, 4), 256, 0, stream>>>(P, Vt, spart, out);
}